// Round 4
// baseline (282.915 us; speedup 1.0000x reference)
//
#include <hip/hip_runtime.h>

// x: (16, 10, 512, 512) fp32. out: (16, 8, 512, 512) fp32.
// Per pixel: mag = sqrt(x[8]^2 + x[9]^2); out[c] = (c == argmax(x[0..7])) ? mag : 0.
// Streaming: 167.8 MB read + 134.2 MB write, HBM floor ~50 us @ ~6 TB/s mixed.
// R4: isolate the one untested R2 lever — 2x float4/thread (20 loads in
//     flight, half the addr-setup per byte, 8K waves = one residency pass)
//     with PLAIN stores (R2 proved nt stores 2x-amplify WRITE_SIZE) and nt
//     loads (R3 proved ~10us win).

typedef float f4 __attribute__((ext_vector_type(4)));

constexpr int HW    = 512 * 512;
constexpr int HW4   = HW / 4;        // 65536 float4s per (b,c) plane
constexpr int B     = 16;
constexpr int CIN   = 10;
constexpr int COUT  = 8;

__global__ __launch_bounds__(256) void HistogramLayer_52776558133573_kernel(
    const f4* __restrict__ x, f4* __restrict__ out) {
    unsigned tid = blockIdx.x * blockDim.x + threadIdx.x;  // 0 .. 524287, exact
    unsigned b   = tid >> 15;            // / (HW4/2)
    unsigned p   = (tid & 32767) << 1;   // float4 index within plane, pairs

    const f4* xb = x + (size_t)b * CIN * HW4 + p;
    f4*       ob = out + (size_t)b * COUT * HW4 + p;

    // All 20 loads issued up front, nontemporal (evict-first in L2).
    f4 v[CIN][2];
#pragma unroll
    for (int c = 0; c < CIN; ++c) {
#pragma unroll
        for (int u = 0; u < 2; ++u)
            v[c][u] = __builtin_nontemporal_load(&xb[(size_t)c * HW4 + u]);
    }

    f4 mag[2];
    int ixs[2][4];
#pragma unroll
    for (int u = 0; u < 2; ++u) {
        // argmax over channels 0..7 (strict > => first-max, matches jnp.argmax)
        f4 best = v[0][u];
        int ix = 0, iy = 0, iz = 0, iw = 0;
#pragma unroll
        for (int c = 1; c < COUT; ++c) {
            f4 t = v[c][u];
            if (t.x > best.x) { best.x = t.x; ix = c; }
            if (t.y > best.y) { best.y = t.y; iy = c; }
            if (t.z > best.z) { best.z = t.z; iz = c; }
            if (t.w > best.w) { best.w = t.w; iw = c; }
        }
        ixs[u][0] = ix; ixs[u][1] = iy; ixs[u][2] = iz; ixs[u][3] = iw;

        f4 g0 = v[8][u], g1 = v[9][u];
        mag[u].x = sqrtf(g0.x * g0.x + g1.x * g1.x);
        mag[u].y = sqrtf(g0.y * g0.y + g1.y * g1.y);
        mag[u].z = sqrtf(g0.z * g0.z + g1.z * g1.z);
        mag[u].w = sqrtf(g0.w * g0.w + g1.w * g1.w);
    }

    // Plain stores through L2 (write-combining, no amplification).
    // Both halves' stores to the same plane adjacent: 32B contiguous per lane.
#pragma unroll
    for (int c = 0; c < COUT; ++c) {
#pragma unroll
        for (int u = 0; u < 2; ++u) {
            f4 o;
            o.x = (ixs[u][0] == c) ? mag[u].x : 0.0f;
            o.y = (ixs[u][1] == c) ? mag[u].y : 0.0f;
            o.z = (ixs[u][2] == c) ? mag[u].z : 0.0f;
            o.w = (ixs[u][3] == c) ? mag[u].w : 0.0f;
            ob[(size_t)c * HW4 + u] = o;
        }
    }
}

extern "C" void kernel_launch(void* const* d_in, const int* in_sizes, int n_in,
                              void* d_out, int out_size, void* d_ws, size_t ws_size,
                              hipStream_t stream) {
    const f4* x = (const f4*)d_in[0];
    f4* out = (f4*)d_out;
    const int total_threads = B * HW4 / 2;        // 524,288
    const int block = 256;
    const int grid = total_threads / block;       // 2048, exact
    HistogramLayer_52776558133573_kernel<<<grid, block, 0, stream>>>(x, out);
}

// Round 5
// 261.083 us; speedup vs baseline: 1.0836x; 1.0836x over previous
//
#include <hip/hip_runtime.h>

// x: (16, 10, 512, 512) fp32. out: (16, 8, 512, 512) fp32.
// Per pixel: mag = sqrt(x[8]^2 + x[9]^2); out[c] = (c == argmax(x[0..7])) ? mag : 0.
// Streaming: 167.8 MB read + 134.2 MB write, HBM floor ~50 us @ ~6 TB/s mixed.
// R5: 2x f4/thread with CORRECT coalescing (R4's p=2*tid gave 32B inter-lane
//     stride -> half-coalesced instructions; that, not ILP, was the regression).
//     Block covers 512 consecutive f4s; thread t handles base+t and base+t+256
//     so every load/store instruction is a contiguous 1KB wave access.
//     nt loads (R3: +10us), plain stores (R2: nt stores 2x WRITE_SIZE).

typedef float f4 __attribute__((ext_vector_type(4)));

constexpr int HW    = 512 * 512;
constexpr int HW4   = HW / 4;        // 65536 f4s per (b,c) plane
constexpr int B     = 16;
constexpr int CIN   = 10;
constexpr int COUT  = 8;

__global__ __launch_bounds__(256) void HistogramLayer_52776558133573_kernel(
    const f4* __restrict__ x, f4* __restrict__ out) {
    // Block covers 512 consecutive f4 positions (within one batch: 512 | 65536).
    unsigned j0 = blockIdx.x * 512 + threadIdx.x;   // f4 position, half 0
    unsigned b  = j0 >> 16;                          // batch
    unsigned p  = j0 & (HW4 - 1);                    // f4 index within plane

    const f4* xb = x + (size_t)b * CIN * HW4 + p;
    f4*       ob = out + (size_t)b * COUT * HW4 + p;

    // All 20 loads issued up front, nontemporal; each instruction is a
    // contiguous 64-lane x 16B access (halves: +0 and +256).
    f4 v[CIN][2];
#pragma unroll
    for (int c = 0; c < CIN; ++c) {
#pragma unroll
        for (int u = 0; u < 2; ++u)
            v[c][u] = __builtin_nontemporal_load(&xb[(size_t)c * HW4 + u * 256]);
    }

    f4 mag[2];
    int ixs[2][4];
#pragma unroll
    for (int u = 0; u < 2; ++u) {
        // argmax over channels 0..7 (strict > => first-max, matches jnp.argmax)
        f4 best = v[0][u];
        int ix = 0, iy = 0, iz = 0, iw = 0;
#pragma unroll
        for (int c = 1; c < COUT; ++c) {
            f4 t = v[c][u];
            if (t.x > best.x) { best.x = t.x; ix = c; }
            if (t.y > best.y) { best.y = t.y; iy = c; }
            if (t.z > best.z) { best.z = t.z; iz = c; }
            if (t.w > best.w) { best.w = t.w; iw = c; }
        }
        ixs[u][0] = ix; ixs[u][1] = iy; ixs[u][2] = iz; ixs[u][3] = iw;

        f4 g0 = v[8][u], g1 = v[9][u];
        mag[u].x = sqrtf(g0.x * g0.x + g1.x * g1.x);
        mag[u].y = sqrtf(g0.y * g0.y + g1.y * g1.y);
        mag[u].z = sqrtf(g0.z * g0.z + g1.z * g1.z);
        mag[u].w = sqrtf(g0.w * g0.w + g1.w * g1.w);
    }

    // Plain stores through L2 (write-combining, no amplification).
#pragma unroll
    for (int c = 0; c < COUT; ++c) {
#pragma unroll
        for (int u = 0; u < 2; ++u) {
            f4 o;
            o.x = (ixs[u][0] == c) ? mag[u].x : 0.0f;
            o.y = (ixs[u][1] == c) ? mag[u].y : 0.0f;
            o.z = (ixs[u][2] == c) ? mag[u].z : 0.0f;
            o.w = (ixs[u][3] == c) ? mag[u].w : 0.0f;
            ob[(size_t)c * HW4 + u * 256] = o;
        }
    }
}

extern "C" void kernel_launch(void* const* d_in, const int* in_sizes, int n_in,
                              void* d_out, int out_size, void* d_ws, size_t ws_size,
                              hipStream_t stream) {
    const f4* x = (const f4*)d_in[0];
    f4* out = (f4*)d_out;
    const int block = 256;
    const int grid = B * HW4 / 512;               // 2048 blocks, exact
    HistogramLayer_52776558133573_kernel<<<grid, block, 0, stream>>>(x, out);
}